// Round 3
// baseline (340.217 us; speedup 1.0000x reference)
//
#include <hip/hip_runtime.h>
#include <math.h>

constexpr int kB = 8;
constexpr int kS = 512;
constexpr int kH = 768;

// Staged values are scaled by 2*log2(e) so exp2(q~+k~) = e^{2x}; tanh(x) = 1 - 2/(e^{2x}+1).
// vb and sum(va) are additive constants over the softmax axis -> dropped.
constexpr float kTanhScale = 2.8853900817779268f;  // 2*log2(e)

__device__ __forceinline__ float waveMax(float v) {
#pragma unroll
    for (int off = 32; off > 0; off >>= 1) v = fmaxf(v, __shfl_xor(v, off, 64));
    return v;
}
__device__ __forceinline__ float waveSum(float v) {
#pragma unroll
    for (int off = 32; off > 0; off >>= 1) v += __shfl_xor(v, off, 64);
    return v;
}

// ---------------- K1: z=0: Wq2[b,t,h] = (out·Wa^T + b)*scale  (row-major)
//                      z=1: UkT2[b,h,s] = (out·Ua^T + b)*scale (transposed via LDS tile)
__global__ __launch_bounds__(256) void k1_dual_gemm(
    const float* __restrict__ A,
    const float* __restrict__ W0, const float* __restrict__ bias0,
    const float* __restrict__ W1, const float* __restrict__ bias1,
    float* __restrict__ out0, float* __restrict__ out1)
{
    const float* W    = blockIdx.z ? W1 : W0;
    const float* bias = blockIdx.z ? bias1 : bias0;

    __shared__ float smem[4160];                 // aliased: As[16][68] | Ws[16][68] ; stage[64][65]
    float (*As)[68] = (float(*)[68])smem;
    float (*Ws)[68] = (float(*)[68])(smem + 16 * 68);

    const int m0 = blockIdx.y * 64;
    const int n0 = blockIdx.x * 64;
    const int tid = threadIdx.x;
    const int lrow = tid >> 2;
    const int lk4  = (tid & 3) << 2;
    const int is = tid >> 4;
    const int js = tid & 15;

    const float* arow = A + (size_t)(m0 + lrow) * kH + lk4;
    const float* wrow = W + (size_t)(n0 + lrow) * kH + lk4;

    float acc[4][4] = {};

    for (int h0 = 0; h0 < kH; h0 += 16) {
        float4 av = *(const float4*)(arow + h0);
        float4 wv = *(const float4*)(wrow + h0);
        __syncthreads();
        As[lk4 + 0][lrow] = av.x;
        As[lk4 + 1][lrow] = av.y;
        As[lk4 + 2][lrow] = av.z;
        As[lk4 + 3][lrow] = av.w;
        Ws[lk4 + 0][lrow] = wv.x;
        Ws[lk4 + 1][lrow] = wv.y;
        Ws[lk4 + 2][lrow] = wv.z;
        Ws[lk4 + 3][lrow] = wv.w;
        __syncthreads();
#pragma unroll
        for (int kk = 0; kk < 16; ++kk) {
            const float* ap = &As[kk][is << 2];
            const float* bp = &Ws[kk][js << 2];
            float aa[4], bb[4];
#pragma unroll
            for (int c = 0; c < 4; ++c) { aa[c] = ap[c]; bb[c] = bp[c]; }
#pragma unroll
            for (int i = 0; i < 4; ++i)
#pragma unroll
                for (int j = 0; j < 4; ++j)
                    acc[i][j] = fmaf(aa[i], bb[j], acc[i][j]);
        }
    }

    float4 bv = *(const float4*)(bias + n0 + (js << 2));

    if (blockIdx.z == 0) {
#pragma unroll
        for (int i = 0; i < 4; ++i) {
            int row = m0 + (is << 2) + i;
            float4 o;
            o.x = (acc[i][0] + bv.x) * kTanhScale;
            o.y = (acc[i][1] + bv.y) * kTanhScale;
            o.z = (acc[i][2] + bv.z) * kTanhScale;
            o.w = (acc[i][3] + bv.w) * kTanhScale;
            *(float4*)(out0 + (size_t)row * kH + n0 + (js << 2)) = o;
        }
    } else {
        // stage (s_local, h_local), then store transposed [b][h][s] coalesced along s
        __syncthreads();
        float (*stage)[65] = (float(*)[65])smem;
        const float bb[4] = {bv.x, bv.y, bv.z, bv.w};
#pragma unroll
        for (int i = 0; i < 4; ++i)
#pragma unroll
            for (int j = 0; j < 4; ++j)
                stage[(is << 2) + i][(js << 2) + j] = (acc[i][j] + bb[j]) * kTanhScale;
        __syncthreads();

        const int b = m0 >> 9;                   // 64 | 512 -> tiles never straddle batches
        const int sbase = m0 & (kS - 1);
        const int hl = tid >> 2;                 // 0..63
        const int sq = (tid & 3) << 4;           // 0,16,32,48
        float* obase = out1 + ((size_t)b * kH + n0 + hl) * kS + sbase + sq;
#pragma unroll
        for (int u = 0; u < 16; u += 4) {
            float4 o = {stage[sq + u + 0][hl], stage[sq + u + 1][hl],
                        stage[sq + u + 2][hl], stage[sq + u + 3][hl]};
            *(float4*)(obase + u) = o;
        }
    }
}

// ---------------- K2a: work list of (b, j-tile[JT], k-wave[64]) items.
template <int JT>
__global__ void k2a_worklist(const int* __restrict__ mask, int* __restrict__ wl)
{
    __shared__ int ne[kB], off[kB];
    const int tid = threadIdx.x;
    if (tid < kB) {
        int start = mask[2 * tid];
        int njt = (kS - start + JT - 1) / JT;
        int nkw = (start + 63) >> 6;
        ne[tid] = njt * nkw;
    }
    __syncthreads();
    if (tid == 0) {
        int s = 0;
        for (int b = 0; b < kB; ++b) { off[b] = s; s += ne[b]; }
        wl[0] = s;
    }
    __syncthreads();
    for (int b = 0; b < kB; ++b) {
        int start = mask[2 * b];
        int nkw = (start + 63) >> 6;
        int n = ne[b], base = off[b];
        for (int t = tid; t < n; t += blockDim.x) {
            int jt = t / nkw, kt = t - jt * nkw;
            wl[1 + base + t] = (b << 16) | (jt << 8) | kt;
        }
    }
}

// ---------------- K2: one wave per item; lane = k; JT j-rows; h in 8-reg chunks.
// score~[b,j,k] = -2 * sum_h va[h] * rcp(exp2(Wq2[b,start+j,h] + UkT2[b,h,k]) + 1)
template <int JT>
__global__ __launch_bounds__(256) void k2_scores(
    const float* __restrict__ Wq2, const float* __restrict__ UkT2,
    const float* __restrict__ va, const int* __restrict__ mask,
    const int* __restrict__ wl, float* __restrict__ scores)
{
    const int ntiles = wl[0];
    const int lane = threadIdx.x & 63;
    const int wslot = (blockIdx.x << 2) | (threadIdx.x >> 6);
    const int nslots = gridDim.x << 2;

    for (int w = wslot; w < ntiles; w += nslots) {
        const int e = __builtin_amdgcn_readfirstlane(wl[1 + w]);
        const int b  = e >> 16;
        const int jt = (e >> 8) & 255;
        const int kt = e & 255;
        const int start = __builtin_amdgcn_readfirstlane(mask[2 * b]);
        const int jmax = kS - start;
        const int j0 = jt * JT;
        const int k0 = kt << 6;

        const float* uk0 = UkT2 + (size_t)b * kH * kS + k0 + lane;
        const float* wqb = Wq2 + (size_t)b * kS * kH;
        const float* wqr[JT];
#pragma unroll
        for (int j = 0; j < JT; ++j) {
            int t = start + j0 + j;
            if (t > kS - 1) t = kS - 1;          // straddle rows: computed, never stored
            wqr[j] = wqb + (size_t)t * kH;
        }
        float acc[JT];
#pragma unroll
        for (int j = 0; j < JT; ++j) acc[j] = 0.0f;

        for (int h0 = 0; h0 < kH; h0 += 8) {
            float uk[8];
#pragma unroll
            for (int c = 0; c < 8; ++c) uk[c] = uk0[(size_t)(h0 + c) * kS];
#pragma unroll
            for (int c = 0; c < 8; ++c) {
                const float vc = va[h0 + c];
#pragma unroll
                for (int j = 0; j < JT; ++j) {
                    float r = __builtin_amdgcn_rcpf(exp2f(wqr[j][h0 + c] + uk[c]) + 1.0f);
                    acc[j] = fmaf(vc, r, acc[j]);
                }
            }
        }

        float* srow = scores + ((size_t)b * kS + j0) * kS + k0 + lane;
#pragma unroll
        for (int j = 0; j < JT; ++j)
            if (j0 + j < jmax) srow[(size_t)j * kS] = -2.0f * acc[j];
    }
}

// ---------------- K3: row softmax over k < start; exact zeros elsewhere.
__global__ __launch_bounds__(256) void k3_softmax(
    float* __restrict__ attn, const int* __restrict__ mask)
{
    const int bx = blockIdx.x;
    const int b = bx >> 9;
    const int j = bx & (kS - 1);
    const int start = mask[2 * b];
    float* row = attn + ((size_t)b * kS + j) * kS;
    const int tid = threadIdx.x;

    if (j >= kS - start) {
        row[tid] = 0.0f;
        row[tid + 256] = 0.0f;
        return;
    }

    float v0 = (tid < start) ? row[tid] : -1e30f;
    float v1 = (tid + 256 < start) ? row[tid + 256] : -1e30f;

    __shared__ float red[4];
    const int wid = tid >> 6;

    float m = waveMax(fmaxf(v0, v1));
    if ((tid & 63) == 0) red[wid] = m;
    __syncthreads();
    m = fmaxf(fmaxf(red[0], red[1]), fmaxf(red[2], red[3]));
    __syncthreads();

    float e0 = (tid < start) ? __expf(v0 - m) : 0.0f;
    float e1 = (tid + 256 < start) ? __expf(v1 - m) : 0.0f;
    float s = waveSum(e0 + e1);
    if ((tid & 63) == 0) red[wid] = s;
    __syncthreads();
    s = red[0] + red[1] + red[2] + red[3];

    float inv = __builtin_amdgcn_rcpf(s);
    row[tid] = e0 * inv;
    row[tid + 256] = e1 * inv;
}

// ---------------- K4: ctx[b,j,h] = sum_k attn[b,j,k] * outputs[b,k,h], K bounded by start.
__global__ __launch_bounds__(256) void k4_context(
    const float* __restrict__ attn, const float* __restrict__ outs,
    const int* __restrict__ mask, float* __restrict__ ctx)
{
    const int b = blockIdx.z;
    const int start = mask[2 * b];
    const int kmax = (start + 15) & ~15;
    const int m0 = blockIdx.y * 64;
    const int n0 = blockIdx.x * 64;

    __shared__ float As[16][68];
    __shared__ float Bs[16][68];

    const int tid = threadIdx.x;
    const int lrow = tid >> 2;
    const int lk4  = (tid & 3) << 2;
    const int brow = tid >> 4;
    const int bh4  = (tid & 15) << 2;
    const int is = tid >> 4;
    const int js = tid & 15;

    const float* arow = attn + ((size_t)b * kS + m0 + lrow) * kS + lk4;
    const float* bbase = outs + (size_t)b * kS * kH + n0 + bh4;

    float acc[4][4] = {};

    for (int k0 = 0; k0 < kmax; k0 += 16) {
        float4 av = *(const float4*)(arow + k0);
        float4 bv = *(const float4*)(bbase + (size_t)(k0 + brow) * kH);
        __syncthreads();
        As[lk4 + 0][lrow] = av.x;
        As[lk4 + 1][lrow] = av.y;
        As[lk4 + 2][lrow] = av.z;
        As[lk4 + 3][lrow] = av.w;
        *(float4*)&Bs[brow][bh4] = bv;
        __syncthreads();
#pragma unroll
        for (int kk = 0; kk < 16; ++kk) {
            const float* ap = &As[kk][is << 2];
            const float* bp = &Bs[kk][js << 2];
            float aa[4], bb[4];
#pragma unroll
            for (int c = 0; c < 4; ++c) { aa[c] = ap[c]; bb[c] = bp[c]; }
#pragma unroll
            for (int i = 0; i < 4; ++i)
#pragma unroll
                for (int j = 0; j < 4; ++j)
                    acc[i][j] = fmaf(aa[i], bb[j], acc[i][j]);
        }
    }

#pragma unroll
    for (int i = 0; i < 4; ++i) {
        int row = m0 + (is << 2) + i;
        float4 o = {acc[i][0], acc[i][1], acc[i][2], acc[i][3]};
        *(float4*)(ctx + ((size_t)b * kS + row) * kH + n0 + (js << 2)) = o;
    }
}

extern "C" void kernel_launch(void* const* d_in, const int* in_sizes, int n_in,
                              void* d_out, int out_size, void* d_ws, size_t ws_size,
                              hipStream_t stream)
{
    const float* outputs = (const float*)d_in[0];
    const int*   mask    = (const int*)d_in[1];
    const float* Wa_w    = (const float*)d_in[2];
    const float* Wa_b    = (const float*)d_in[3];
    const float* Ua_w    = (const float*)d_in[4];
    const float* Ua_b    = (const float*)d_in[5];
    const float* Va_w    = (const float*)d_in[6];
    // Va_b and sum(va) cancel in softmax.

    float* attn = (float*)d_out;                          // (B,S,S)
    float* ctx  = attn + (size_t)kB * kS * kS;            // (B,S,H)
    float* UkT2 = ctx;                                    // [b][h][s] — ctx region free until K4

    constexpr size_t kWqBytes = (size_t)kB * kS * kH * sizeof(float);
    constexpr size_t kWl2Bytes = 64 * 1024;               // JT=2 worklist (<=5120 entries max)
    constexpr size_t kWl4Bytes = 16 * 1024;               // JT=4 worklist (<=2560 entries max)

    const bool jt2 = (ws_size >= kWl2Bytes + kWqBytes);
    int* wl = (int*)d_ws;
    float* Wq2 = (float*)((char*)d_ws + (jt2 ? kWl2Bytes : kWl4Bytes));

    // K1: Wq2 (scaled, row-major) and UkT2 (scaled, transposed)
    k1_dual_gemm<<<dim3(kH / 64, (kB * kS) / 64, 2), 256, 0, stream>>>(
        outputs, Wa_w, Wa_b, Ua_w, Ua_b, Wq2, UkT2);

    // K2a + K2: scores into attn region
    if (jt2) {
        k2a_worklist<2><<<dim3(1), 256, 0, stream>>>(mask, wl);
        k2_scores<2><<<dim3(1024), 256, 0, stream>>>(Wq2, UkT2, Va_w, mask, wl, attn);
    } else {
        k2a_worklist<4><<<dim3(1), 256, 0, stream>>>(mask, wl);
        k2_scores<4><<<dim3(1024), 256, 0, stream>>>(Wq2, UkT2, Va_w, mask, wl, attn);
    }

    // K3: softmax + exact-zero masking (writes every element of attn)
    k3_softmax<<<dim3(kB * kS), 256, 0, stream>>>(attn, mask);

    // K4: contexts (writes every element of ctx, overwriting UkT2 scratch)
    k4_context<<<dim3(kH / 64, kS / 64, kB), 256, 0, stream>>>(attn, outputs, mask, ctx);
}

// Round 4
// 336.422 us; speedup vs baseline: 1.0113x; 1.0113x over previous
//
#include <hip/hip_runtime.h>
#include <math.h>

constexpr int kB = 8;
constexpr int kS = 512;
constexpr int kH = 768;

// Staged values are scaled by 2*log2(e) so v_exp (=2^x) gives e^{2x}.
// tanh(x) = 1 - 2/(e^{2x}+1); additive constants (vb, sum(va)) cancel in softmax.
constexpr float kTanhScale = 2.8853900817779268f;  // 2*log2(e)

__device__ __forceinline__ float native_exp2(float x) {
    float r;
    asm("v_exp_f32 %0, %1" : "=v"(r) : "v"(x));
    return r;
}

__device__ __forceinline__ float waveMax(float v) {
#pragma unroll
    for (int off = 32; off > 0; off >>= 1) v = fmaxf(v, __shfl_xor(v, off, 64));
    return v;
}
__device__ __forceinline__ float waveSum(float v) {
#pragma unroll
    for (int off = 32; off > 0; off >>= 1) v += __shfl_xor(v, off, 64);
    return v;
}

// ---------------- K1: z=0: Wq2[b,t,h] = (out·Wa^T + b)*scale  (row-major)
//                      z=1: UkT2[b,h,s] = (out·Ua^T + b)*scale (stored transposed)
// 64(M) x 128(N) tile, BK=16, 256 threads, 4x8 micro. Grid 6x64x2 = 768 blocks = 3/CU.
__global__ __launch_bounds__(256) void k1_dual_gemm(
    const float* __restrict__ A,
    const float* __restrict__ W0, const float* __restrict__ bias0,
    const float* __restrict__ W1, const float* __restrict__ bias1,
    float* __restrict__ out0, float* __restrict__ out1)
{
    const float* W    = blockIdx.z ? W1 : W0;
    const float* bias = blockIdx.z ? bias1 : bias0;

    __shared__ float As[16][68];    // k-major A tile (64 m)
    __shared__ float Ws[16][132];   // k-major W tile (128 n)

    const int m0 = blockIdx.y * 64;
    const int n0 = blockIdx.x * 128;
    const int tid = threadIdx.x;

    const int srow = tid >> 2;          // 0..63
    const int sk4  = (tid & 3) << 2;    // 0,4,8,12

    const float* arow  = A + (size_t)(m0 + srow) * kH + sk4;
    const float* wrow0 = W + (size_t)(n0 + srow) * kH + sk4;
    const float* wrow1 = W + (size_t)(n0 + 64 + srow) * kH + sk4;

    const int im = tid >> 4;   // 0..15 -> m = im*4
    const int in = tid & 15;   // 0..15 -> n = in*8

    float acc[4][8] = {};

    for (int h0 = 0; h0 < kH; h0 += 16) {
        float4 av  = *(const float4*)(arow + h0);
        float4 wv0 = *(const float4*)(wrow0 + h0);
        float4 wv1 = *(const float4*)(wrow1 + h0);
        __syncthreads();
        As[sk4 + 0][srow] = av.x;
        As[sk4 + 1][srow] = av.y;
        As[sk4 + 2][srow] = av.z;
        As[sk4 + 3][srow] = av.w;
        Ws[sk4 + 0][srow] = wv0.x;
        Ws[sk4 + 1][srow] = wv0.y;
        Ws[sk4 + 2][srow] = wv0.z;
        Ws[sk4 + 3][srow] = wv0.w;
        Ws[sk4 + 0][64 + srow] = wv1.x;
        Ws[sk4 + 1][64 + srow] = wv1.y;
        Ws[sk4 + 2][64 + srow] = wv1.z;
        Ws[sk4 + 3][64 + srow] = wv1.w;
        __syncthreads();
#pragma unroll
        for (int kk = 0; kk < 16; ++kk) {
            float aa[4], bb[8];
            *(float4*)aa = *(const float4*)&As[kk][im << 2];
            *(float4*)(bb + 0) = *(const float4*)&Ws[kk][(in << 3) + 0];
            *(float4*)(bb + 4) = *(const float4*)&Ws[kk][(in << 3) + 4];
#pragma unroll
            for (int i = 0; i < 4; ++i)
#pragma unroll
                for (int j = 0; j < 8; ++j)
                    acc[i][j] = fmaf(aa[i], bb[j], acc[i][j]);
        }
    }

    float bb8[8];
    *(float4*)(bb8 + 0) = *(const float4*)(bias + n0 + (in << 3) + 0);
    *(float4*)(bb8 + 4) = *(const float4*)(bias + n0 + (in << 3) + 4);

    if (blockIdx.z == 0) {
#pragma unroll
        for (int i = 0; i < 4; ++i) {
            int row = m0 + (im << 2) + i;
            float o[8];
#pragma unroll
            for (int j = 0; j < 8; ++j) o[j] = (acc[i][j] + bb8[j]) * kTanhScale;
            *(float4*)(out0 + (size_t)row * kH + n0 + (in << 3) + 0) = *(float4*)(o + 0);
            *(float4*)(out0 + (size_t)row * kH + n0 + (in << 3) + 4) = *(float4*)(o + 4);
        }
    } else {
        // transposed store: UkT2[b][h][s], 16B chunks along s
        const int b = m0 >> 9;                  // 64 | 512: tiles never straddle batches
        const int sbase = (m0 & (kS - 1)) + (im << 2);
#pragma unroll
        for (int j = 0; j < 8; ++j) {
            int h = n0 + (in << 3) + j;
            float4 o = {(acc[0][j] + bb8[j]) * kTanhScale,
                        (acc[1][j] + bb8[j]) * kTanhScale,
                        (acc[2][j] + bb8[j]) * kTanhScale,
                        (acc[3][j] + bb8[j]) * kTanhScale};
            *(float4*)(out1 + ((size_t)b * kH + h) * kS + sbase) = o;
        }
    }
}

// ---------------- K2a: work list of (b, j-tile[JT], k-wave[64]) items.
template <int JT>
__global__ void k2a_worklist(const int* __restrict__ mask, int* __restrict__ wl)
{
    __shared__ int ne[kB], off[kB];
    const int tid = threadIdx.x;
    if (tid < kB) {
        int start = mask[2 * tid];
        int njt = (kS - start + JT - 1) / JT;
        int nkw = (start + 63) >> 6;
        ne[tid] = njt * nkw;
    }
    __syncthreads();
    if (tid == 0) {
        int s = 0;
        for (int b = 0; b < kB; ++b) { off[b] = s; s += ne[b]; }
        wl[0] = s;
    }
    __syncthreads();
    for (int b = 0; b < kB; ++b) {
        int start = mask[2 * b];
        int nkw = (start + 63) >> 6;
        int n = ne[b], base = off[b];
        for (int t = tid; t < n; t += blockDim.x) {
            int jt = t / nkw, kt = t - jt * nkw;
            wl[1 + base + t] = (b << 16) | (jt << 8) | kt;
        }
    }
}

// ---------------- K2: one wave per item; lane = k; JT j-rows; h in 8-reg chunks, 2-deep prefetch.
// score~[b,j,k] = -2 * sum_h va[h] * rcp(exp(2*(Wq[...]+Uk[...])) + 1)
template <int JT>
__global__ __launch_bounds__(256) void k2_scores(
    const float* __restrict__ Wq2, const float* __restrict__ UkT2,
    const float* __restrict__ va, const int* __restrict__ mask,
    const int* __restrict__ wl, float* __restrict__ scores)
{
    const int ntiles = wl[0];
    const int lane = threadIdx.x & 63;
    const int wslot = (blockIdx.x << 2) | (threadIdx.x >> 6);
    const int nslots = gridDim.x << 2;

    for (int w = wslot; w < ntiles; w += nslots) {
        const int e = __builtin_amdgcn_readfirstlane(wl[1 + w]);
        const int b  = e >> 16;
        const int jt = (e >> 8) & 255;
        const int kt = e & 255;
        const int start = __builtin_amdgcn_readfirstlane(mask[2 * b]);
        const int jmax = kS - start;
        const int j0 = jt * JT;
        const int k0 = kt << 6;

        const float* uk0 = UkT2 + (size_t)b * kH * kS + k0 + lane;
        const float* wqb = Wq2 + (size_t)b * kS * kH;
        const float* wqr[JT];
#pragma unroll
        for (int j = 0; j < JT; ++j) {
            int t = start + j0 + j;
            if (t > kS - 1) t = kS - 1;          // straddle rows: computed, never stored
            wqr[j] = wqb + (size_t)t * kH;
        }
        float acc[JT];
#pragma unroll
        for (int j = 0; j < JT; ++j) acc[j] = 0.0f;

        float uk[8];
#pragma unroll
        for (int c = 0; c < 8; ++c) uk[c] = uk0[(size_t)c * kS];

        for (int h0 = 0; h0 < kH; h0 += 8) {
            float uknx[8];
            if (h0 + 8 < kH) {
#pragma unroll
                for (int c = 0; c < 8; ++c) uknx[c] = uk0[(size_t)(h0 + 8 + c) * kS];
            }
#pragma unroll
            for (int c = 0; c < 8; ++c) {
                const float vc = va[h0 + c];
#pragma unroll
                for (int j = 0; j < JT; ++j) {
                    float x = wqr[j][h0 + c] + uk[c];
                    float r = __builtin_amdgcn_rcpf(native_exp2(x) + 1.0f);
                    acc[j] = fmaf(vc, r, acc[j]);
                }
            }
#pragma unroll
            for (int c = 0; c < 8; ++c) uk[c] = uknx[c];
        }

        float* srow = scores + ((size_t)b * kS + j0) * kS + k0 + lane;
#pragma unroll
        for (int j = 0; j < JT; ++j)
            if (j0 + j < jmax) srow[(size_t)j * kS] = -2.0f * acc[j];
    }
}

// ---------------- K3: row softmax over k < start; exact zeros elsewhere.
__global__ __launch_bounds__(256) void k3_softmax(
    float* __restrict__ attn, const int* __restrict__ mask)
{
    const int bx = blockIdx.x;
    const int b = bx >> 9;
    const int j = bx & (kS - 1);
    const int start = mask[2 * b];
    float* row = attn + ((size_t)b * kS + j) * kS;
    const int tid = threadIdx.x;

    if (j >= kS - start) {
        row[tid] = 0.0f;
        row[tid + 256] = 0.0f;
        return;
    }

    float v0 = (tid < start) ? row[tid] : -1e30f;
    float v1 = (tid + 256 < start) ? row[tid + 256] : -1e30f;

    __shared__ float red[4];
    const int wid = tid >> 6;

    float m = waveMax(fmaxf(v0, v1));
    if ((tid & 63) == 0) red[wid] = m;
    __syncthreads();
    m = fmaxf(fmaxf(red[0], red[1]), fmaxf(red[2], red[3]));
    __syncthreads();

    float e0 = (tid < start) ? __expf(v0 - m) : 0.0f;
    float e1 = (tid + 256 < start) ? __expf(v1 - m) : 0.0f;
    float s = waveSum(e0 + e1);
    if ((tid & 63) == 0) red[wid] = s;
    __syncthreads();
    s = red[0] + red[1] + red[2] + red[3];

    float inv = __builtin_amdgcn_rcpf(s);
    row[tid] = e0 * inv;
    row[tid + 256] = e1 * inv;
}

// ---------------- K4: ctx[b,j,h] = sum_k attn[b,j,k] * outputs[b,k,h], K bounded by start.
__global__ __launch_bounds__(256) void k4_context(
    const float* __restrict__ attn, const float* __restrict__ outs,
    const int* __restrict__ mask, float* __restrict__ ctx)
{
    const int b = blockIdx.z;
    const int start = mask[2 * b];
    const int kmax = (start + 15) & ~15;
    const int m0 = blockIdx.y * 64;
    const int n0 = blockIdx.x * 64;

    __shared__ float As[16][68];
    __shared__ float Bs[16][68];

    const int tid = threadIdx.x;
    const int lrow = tid >> 2;
    const int lk4  = (tid & 3) << 2;
    const int brow = tid >> 4;
    const int bh4  = (tid & 15) << 2;
    const int is = tid >> 4;
    const int js = tid & 15;

    const float* arow = attn + ((size_t)b * kS + m0 + lrow) * kS + lk4;
    const float* bbase = outs + (size_t)b * kS * kH + n0 + bh4;

    float acc[4][4] = {};

    for (int k0 = 0; k0 < kmax; k0 += 16) {
        float4 av = *(const float4*)(arow + k0);
        float4 bv = *(const float4*)(bbase + (size_t)(k0 + brow) * kH);
        __syncthreads();
        As[lk4 + 0][lrow] = av.x;
        As[lk4 + 1][lrow] = av.y;
        As[lk4 + 2][lrow] = av.z;
        As[lk4 + 3][lrow] = av.w;
        *(float4*)&Bs[brow][bh4] = bv;
        __syncthreads();
#pragma unroll
        for (int kk = 0; kk < 16; ++kk) {
            const float* ap = &As[kk][is << 2];
            const float* bp = &Bs[kk][js << 2];
            float aa[4], bb[4];
#pragma unroll
            for (int c = 0; c < 4; ++c) { aa[c] = ap[c]; bb[c] = bp[c]; }
#pragma unroll
            for (int i = 0; i < 4; ++i)
#pragma unroll
                for (int j = 0; j < 4; ++j)
                    acc[i][j] = fmaf(aa[i], bb[j], acc[i][j]);
        }
    }

#pragma unroll
    for (int i = 0; i < 4; ++i) {
        int row = m0 + (is << 2) + i;
        float4 o = {acc[i][0], acc[i][1], acc[i][2], acc[i][3]};
        *(float4*)(ctx + ((size_t)b * kS + row) * kH + n0 + (js << 2)) = o;
    }
}

extern "C" void kernel_launch(void* const* d_in, const int* in_sizes, int n_in,
                              void* d_out, int out_size, void* d_ws, size_t ws_size,
                              hipStream_t stream)
{
    const float* outputs = (const float*)d_in[0];
    const int*   mask    = (const int*)d_in[1];
    const float* Wa_w    = (const float*)d_in[2];
    const float* Wa_b    = (const float*)d_in[3];
    const float* Ua_w    = (const float*)d_in[4];
    const float* Ua_b    = (const float*)d_in[5];
    const float* Va_w    = (const float*)d_in[6];
    // Va_b and sum(va) cancel in softmax.

    float* attn = (float*)d_out;                          // (B,S,S)
    float* ctx  = attn + (size_t)kB * kS * kS;            // (B,S,H)
    float* UkT2 = ctx;                                    // [b][h][s] — ctx region free until K4

    constexpr size_t kWqBytes = (size_t)kB * kS * kH * sizeof(float);
    constexpr size_t kWl2Bytes = 64 * 1024;
    constexpr size_t kWl4Bytes = 16 * 1024;

    const bool jt2 = (ws_size >= kWl2Bytes + kWqBytes);
    int* wl = (int*)d_ws;
    float* Wq2 = (float*)((char*)d_ws + (jt2 ? kWl2Bytes : kWl4Bytes));

    // K1: Wq2 (scaled, row-major) and UkT2 (scaled, transposed)
    k1_dual_gemm<<<dim3(kH / 128, (kB * kS) / 64, 2), 256, 0, stream>>>(
        outputs, Wa_w, Wa_b, Ua_w, Ua_b, Wq2, UkT2);

    // K2a + K2: scores into attn region
    if (jt2) {
        k2a_worklist<2><<<dim3(1), 256, 0, stream>>>(mask, wl);
        k2_scores<2><<<dim3(1024), 256, 0, stream>>>(Wq2, UkT2, Va_w, mask, wl, attn);
    } else {
        k2a_worklist<4><<<dim3(1), 256, 0, stream>>>(mask, wl);
        k2_scores<4><<<dim3(1024), 256, 0, stream>>>(Wq2, UkT2, Va_w, mask, wl, attn);
    }

    // K3: softmax + exact-zero masking (writes every element of attn)
    k3_softmax<<<dim3(kB * kS), 256, 0, stream>>>(attn, mask);

    // K4: contexts (writes every element of ctx, overwriting UkT2 scratch)
    k4_context<<<dim3(kH / 64, kS / 64, kB), 256, 0, stream>>>(attn, outputs, mask, ctx);
}

// Round 6
// 160.970 us; speedup vs baseline: 2.1135x; 2.0900x over previous
//
#include <hip/hip_runtime.h>

typedef float  f32x4   __attribute__((ext_vector_type(4)));
typedef short  short8  __attribute__((ext_vector_type(8)));
typedef unsigned short ushort8 __attribute__((ext_vector_type(8)));

constexpr int kB = 8;
constexpr int kS = 512;
constexpr int kH = 768;

// Values scaled by 2*log2(e) so exp2 gives e^{2x}; tanh(x) = 1 - 2/(e^{2x}+1).
// Additive constants (vb, sum(va)) cancel in softmax.
constexpr float kTanhScale = 2.8853900817779268f;

__device__ __forceinline__ float native_exp2(float x) {
    float r; asm("v_exp_f32 %0, %1" : "=v"(r) : "v"(x)); return r;
}

__device__ __forceinline__ float waveMax(float v) {
#pragma unroll
    for (int off = 32; off > 0; off >>= 1) v = fmaxf(v, __shfl_xor(v, off, 64));
    return v;
}
__device__ __forceinline__ float waveSum(float v) {
#pragma unroll
    for (int off = 32; off > 0; off >>= 1) v += __shfl_xor(v, off, 64);
    return v;
}

// split x into bf16 hi/lo (truncation; hi+lo = x to ~2^-17 rel)
__device__ __forceinline__ void cvt16(const float4* v, unsigned short* hb, unsigned short* lb) {
#pragma unroll
    for (int q = 0; q < 4; ++q) {
#pragma unroll
        for (int c = 0; c < 4; ++c) {
            float x = (&v[q].x)[c];
            unsigned u = __float_as_uint(x);
            hb[q * 4 + c] = (unsigned short)(u >> 16);
            float hf = __uint_as_float(u & 0xFFFF0000u);
            lb[q * 4 + c] = (unsigned short)(__float_as_uint(x - hf) >> 16);
        }
    }
}

// ---------------- K1 (MFMA): z=0: Eq[m][n]   = exp2((X·Wa^T + b)*s)   row-major [4096][768]
//                             z=1: EkT[b][n][s]= exp2((X·Ua^T + b)*s)  transposed
// BM=128, BN=96, BK=32; 4 waves, each a 64x48 quadrant of 16x16x32 MFMA frags.
// bf16 3-product split: hi*hi + lo*hi + hi*lo.
__global__ __launch_bounds__(256) void k1_mfma(
    const float* __restrict__ A,
    const float* __restrict__ W0, const float* __restrict__ b0,
    const float* __restrict__ W1, const float* __restrict__ b1,
    float* __restrict__ eq, float* __restrict__ ekT)
{
    // LDS: Ahi [128][40]us @0 | Alo @10240 | Bhi [96][40]us @20480 | Blo @28160 (35840 B)
    // z=1 epilogue aliases all of it as float stage[128][97] (49664 B)
    __shared__ char smem[49664];
    unsigned short* Ahi = (unsigned short*)smem;
    unsigned short* Alo = (unsigned short*)(smem + 10240);
    unsigned short* Bhi = (unsigned short*)(smem + 20480);
    unsigned short* Blo = (unsigned short*)(smem + 28160);

    const int z = blockIdx.z;
    const float* W    = z ? W1 : W0;
    const float* bias = z ? b1 : b0;

    const int m0 = blockIdx.y * 128;
    const int n0 = blockIdx.x * 96;
    const int t  = threadIdx.x;

    // staging roles: 2 threads per row, 16 f32 each
    const int ar = t >> 1, ko = (t & 1) << 4;
    const float* agp = A + (size_t)(m0 + ar) * kH + ko;
    const float* wgp = W + (size_t)(n0 + ar) * kH + ko;   // valid when ar < 96
    const bool doB = (ar < 96);

    // mfma roles
    const int wid = t >> 6, lane = t & 63;
    const int wr = wid >> 1, wc = wid & 1;
    const int lr = lane & 15, lk = (lane >> 4) << 3;

    f32x4 acc[4][3];
#pragma unroll
    for (int mi = 0; mi < 4; ++mi)
#pragma unroll
        for (int ni = 0; ni < 3; ++ni)
#pragma unroll
            for (int r = 0; r < 4; ++r) acc[mi][ni][r] = 0.0f;

    for (int h0 = 0; h0 < kH; h0 += 32) {
        float4 av[4], wv[4];
#pragma unroll
        for (int q = 0; q < 4; ++q) av[q] = *(const float4*)(agp + h0 + 4 * q);
        if (doB) {
#pragma unroll
            for (int q = 0; q < 4; ++q) wv[q] = *(const float4*)(wgp + h0 + 4 * q);
        }
        __syncthreads();
        {
            unsigned short hb[16], lb[16];
            cvt16(av, hb, lb);
            *(ushort8*)(Ahi + ar * 40 + ko)     = *(ushort8*)(hb);
            *(ushort8*)(Ahi + ar * 40 + ko + 8) = *(ushort8*)(hb + 8);
            *(ushort8*)(Alo + ar * 40 + ko)     = *(ushort8*)(lb);
            *(ushort8*)(Alo + ar * 40 + ko + 8) = *(ushort8*)(lb + 8);
            if (doB) {
                cvt16(wv, hb, lb);
                *(ushort8*)(Bhi + ar * 40 + ko)     = *(ushort8*)(hb);
                *(ushort8*)(Bhi + ar * 40 + ko + 8) = *(ushort8*)(hb + 8);
                *(ushort8*)(Blo + ar * 40 + ko)     = *(ushort8*)(lb);
                *(ushort8*)(Blo + ar * 40 + ko + 8) = *(ushort8*)(lb + 8);
            }
        }
        __syncthreads();

        short8 ah[4], al_[4], bh[3], bl[3];
#pragma unroll
        for (int mi = 0; mi < 4; ++mi) {
            const int row = wr * 64 + mi * 16 + lr;
            ah[mi]  = *(const short8*)(Ahi + row * 40 + lk);
            al_[mi] = *(const short8*)(Alo + row * 40 + lk);
        }
#pragma unroll
        for (int ni = 0; ni < 3; ++ni) {
            const int row = wc * 48 + ni * 16 + lr;
            bh[ni] = *(const short8*)(Bhi + row * 40 + lk);
            bl[ni] = *(const short8*)(Blo + row * 40 + lk);
        }
#pragma unroll
        for (int mi = 0; mi < 4; ++mi)
#pragma unroll
            for (int ni = 0; ni < 3; ++ni)
                acc[mi][ni] = __builtin_amdgcn_mfma_f32_16x16x32_bf16(ah[mi], bh[ni], acc[mi][ni], 0, 0, 0);
#pragma unroll
        for (int mi = 0; mi < 4; ++mi)
#pragma unroll
            for (int ni = 0; ni < 3; ++ni)
                acc[mi][ni] = __builtin_amdgcn_mfma_f32_16x16x32_bf16(al_[mi], bh[ni], acc[mi][ni], 0, 0, 0);
#pragma unroll
        for (int mi = 0; mi < 4; ++mi)
#pragma unroll
            for (int ni = 0; ni < 3; ++ni)
                acc[mi][ni] = __builtin_amdgcn_mfma_f32_16x16x32_bf16(ah[mi], bl[ni], acc[mi][ni], 0, 0, 0);
    }

    // C/D frag: col = lane&15, row = (lane>>4)*4 + reg
    if (z == 0) {
#pragma unroll
        for (int mi = 0; mi < 4; ++mi)
#pragma unroll
            for (int ni = 0; ni < 3; ++ni) {
                const int mg = m0 + wr * 64 + mi * 16 + ((lane >> 4) << 2);
                const int ng = n0 + wc * 48 + ni * 16 + lr;
                const float bn = bias[ng];
#pragma unroll
                for (int r = 0; r < 4; ++r)
                    eq[(size_t)(mg + r) * kH + ng] = native_exp2((acc[mi][ni][r] + bn) * kTanhScale);
            }
    } else {
        __syncthreads();                       // tile reads done before aliasing LDS
        float* stg = (float*)smem;             // [128][97]
#pragma unroll
        for (int mi = 0; mi < 4; ++mi)
#pragma unroll
            for (int ni = 0; ni < 3; ++ni) {
                const int ml = wr * 64 + mi * 16 + ((lane >> 4) << 2);
                const int nl = wc * 48 + ni * 16 + lr;
                const float bn = bias[n0 + nl];
#pragma unroll
                for (int r = 0; r < 4; ++r)
                    stg[(ml + r) * 97 + nl] = native_exp2((acc[mi][ni][r] + bn) * kTanhScale);
            }
        __syncthreads();
        const int bI = m0 >> 9, sb = m0 & (kS - 1);
        const int s4 = (t & 31) << 2, hb_ = t >> 5;
#pragma unroll
        for (int u = 0; u < 12; ++u) {
            const int h = (u << 3) + hb_;
            float4 o = { stg[(s4 + 0) * 97 + h], stg[(s4 + 1) * 97 + h],
                         stg[(s4 + 2) * 97 + h], stg[(s4 + 3) * 97 + h] };
            *(float4*)(ekT + ((size_t)bI * kH + n0 + h) * kS + sb + s4) = o;
        }
    }
}

// ---------------- K2a: work list of (b, j-pair, k-wave[64]) items.
__global__ void k2a_worklist(const int* __restrict__ mask, int* __restrict__ wl)
{
    __shared__ int ne[kB], off[kB];
    const int tid = threadIdx.x;
    if (tid < kB) {
        int start = mask[2 * tid];
        ne[tid] = ((kS - start + 1) >> 1) * ((start + 63) >> 6);
    }
    __syncthreads();
    if (tid == 0) {
        int s = 0;
        for (int b = 0; b < kB; ++b) { off[b] = s; s += ne[b]; }
        wl[0] = s;
    }
    __syncthreads();
    for (int b = 0; b < kB; ++b) {
        int start = mask[2 * b];
        int nkw = (start + 63) >> 6;
        int n = ne[b], base = off[b];
        for (int t = tid; t < n; t += blockDim.x) {
            int jt = t / nkw, kt = t - jt * nkw;
            wl[1 + base + t] = (b << 16) | (jt << 8) | kt;
        }
    }
}

// ---------------- K2: one wave per item; lane = k; 2 j-rows.
// score~ = -2 * sum_h va[h] * rcp(Eq[b,j,h]*Ek[b,h,k] + 1)
__global__ __launch_bounds__(256) void k2_scores(
    const float* __restrict__ Eq, const float* __restrict__ EkT,
    const float* __restrict__ va, const int* __restrict__ mask,
    const int* __restrict__ wl, float* __restrict__ scores)
{
    const int ntiles = wl[0];
    const int lane = threadIdx.x & 63;
    const int wslot = (blockIdx.x << 2) | (threadIdx.x >> 6);
    const int nslots = gridDim.x << 2;

    for (int w = wslot; w < ntiles; w += nslots) {
        const int e = __builtin_amdgcn_readfirstlane(wl[1 + w]);
        const int b = e >> 16, jt = (e >> 8) & 255, kt = e & 255;
        const int start = __builtin_amdgcn_readfirstlane(mask[2 * b]);
        const int jmax = kS - start;
        const int j0 = jt << 1, k0 = kt << 6;

        const float* ekp = EkT + (size_t)b * kH * kS + k0 + lane;
        int t0 = start + j0;     if (t0 > kS - 1) t0 = kS - 1;
        int t1 = start + j0 + 1; if (t1 > kS - 1) t1 = kS - 1;
        const float* eq0 = Eq + ((size_t)b * kS + t0) * kH;   // FIX: batch offset restored
        const float* eq1 = Eq + ((size_t)b * kS + t1) * kH;

        float a0 = 0.0f, a1 = 0.0f;
        float eA[8], eB[8];
#pragma unroll
        for (int c = 0; c < 8; ++c) eA[c] = ekp[(size_t)c * kS];
#pragma unroll
        for (int c = 0; c < 8; ++c) eB[c] = ekp[(size_t)(8 + c) * kS];

        for (int h0 = 0; h0 < kH; h0 += 16) {
            const bool more = (h0 + 16) < kH;
            float nA[8], nB[8];
            if (more) {
#pragma unroll
                for (int c = 0; c < 8; ++c) nA[c] = ekp[(size_t)(h0 + 16 + c) * kS];
            }
#pragma unroll
            for (int c = 0; c < 8; ++c) {
                const float vc = va[h0 + c];
                float r0 = __builtin_amdgcn_rcpf(fmaf(eq0[h0 + c], eA[c], 1.0f));
                float r1 = __builtin_amdgcn_rcpf(fmaf(eq1[h0 + c], eA[c], 1.0f));
                a0 = fmaf(vc, r0, a0);
                a1 = fmaf(vc, r1, a1);
            }
            if (more) {
#pragma unroll
                for (int c = 0; c < 8; ++c) nB[c] = ekp[(size_t)(h0 + 24 + c) * kS];
#pragma unroll
                for (int c = 0; c < 8; ++c) {
                    const float vc = va[h0 + 8 + c];
                    float r0 = __builtin_amdgcn_rcpf(fmaf(eq0[h0 + 8 + c], eB[c], 1.0f));
                    float r1 = __builtin_amdgcn_rcpf(fmaf(eq1[h0 + 8 + c], eB[c], 1.0f));
                    a0 = fmaf(vc, r0, a0);
                    a1 = fmaf(vc, r1, a1);
                }
#pragma unroll
                for (int c = 0; c < 8; ++c) { eA[c] = nA[c]; eB[c] = nB[c]; }
            } else {
#pragma unroll
                for (int c = 0; c < 8; ++c) {
                    const float vc = va[h0 + 8 + c];
                    float r0 = __builtin_amdgcn_rcpf(fmaf(eq0[h0 + 8 + c], eB[c], 1.0f));
                    float r1 = __builtin_amdgcn_rcpf(fmaf(eq1[h0 + 8 + c], eB[c], 1.0f));
                    a0 = fmaf(vc, r0, a0);
                    a1 = fmaf(vc, r1, a1);
                }
            }
        }

        float* srow = scores + ((size_t)b * kS + j0) * kS + k0 + lane;
        if (j0 < jmax)     srow[0]  = -2.0f * a0;
        if (j0 + 1 < jmax) srow[kS] = -2.0f * a1;
    }
}

// ---------------- K3: row softmax over k < start; exact zeros elsewhere.
__global__ __launch_bounds__(256) void k3_softmax(
    float* __restrict__ attn, const int* __restrict__ mask)
{
    const int bx = blockIdx.x;
    const int b = bx >> 9;
    const int j = bx & (kS - 1);
    const int start = mask[2 * b];
    float* row = attn + ((size_t)b * kS + j) * kS;
    const int tid = threadIdx.x;

    if (j >= kS - start) {
        row[tid] = 0.0f;
        row[tid + 256] = 0.0f;
        return;
    }

    float v0 = (tid < start) ? row[tid] : -1e30f;
    float v1 = (tid + 256 < start) ? row[tid + 256] : -1e30f;

    __shared__ float red[4];
    const int wid = tid >> 6;

    float m = waveMax(fmaxf(v0, v1));
    if ((tid & 63) == 0) red[wid] = m;
    __syncthreads();
    m = fmaxf(fmaxf(red[0], red[1]), fmaxf(red[2], red[3]));
    __syncthreads();

    float e0 = (tid < start) ? __expf(v0 - m) : 0.0f;
    float e1 = (tid + 256 < start) ? __expf(v1 - m) : 0.0f;
    float s = waveSum(e0 + e1);
    if ((tid & 63) == 0) red[wid] = s;
    __syncthreads();
    s = red[0] + red[1] + red[2] + red[3];

    float inv = __builtin_amdgcn_rcpf(s);
    row[tid] = e0 * inv;
    row[tid + 256] = e1 * inv;
}

// ---------------- K4: ctx[b,j,h] = sum_k attn[b,j,k] * outputs[b,k,h], K bounded by start.
__global__ __launch_bounds__(256) void k4_context(
    const float* __restrict__ attn, const float* __restrict__ outs,
    const int* __restrict__ mask, float* __restrict__ ctx)
{
    const int b = blockIdx.z;
    const int start = mask[2 * b];
    const int kmax = (start + 15) & ~15;
    const int m0 = blockIdx.y * 64;
    const int n0 = blockIdx.x * 64;

    __shared__ float As[16][68];
    __shared__ float Bs[16][68];

    const int tid = threadIdx.x;
    const int lrow = tid >> 2;
    const int lk4  = (tid & 3) << 2;
    const int brow = tid >> 4;
    const int bh4  = (tid & 15) << 2;
    const int is = tid >> 4;
    const int js = tid & 15;

    const float* arow = attn + ((size_t)b * kS + m0 + lrow) * kS + lk4;
    const float* bbase = outs + (size_t)b * kS * kH + n0 + bh4;

    float acc[4][4] = {};

    for (int k0 = 0; k0 < kmax; k0 += 16) {
        float4 av = *(const float4*)(arow + k0);
        float4 bv = *(const float4*)(bbase + (size_t)(k0 + brow) * kH);
        __syncthreads();
        As[lk4 + 0][lrow] = av.x;
        As[lk4 + 1][lrow] = av.y;
        As[lk4 + 2][lrow] = av.z;
        As[lk4 + 3][lrow] = av.w;
        *(float4*)&Bs[brow][bh4] = bv;
        __syncthreads();
#pragma unroll
        for (int kk = 0; kk < 16; ++kk) {
            const float* ap = &As[kk][is << 2];
            const float* bp = &Bs[kk][js << 2];
            float aa[4], bb[4];
#pragma unroll
            for (int c = 0; c < 4; ++c) { aa[c] = ap[c]; bb[c] = bp[c]; }
#pragma unroll
            for (int i = 0; i < 4; ++i)
#pragma unroll
                for (int j = 0; j < 4; ++j)
                    acc[i][j] = fmaf(aa[i], bb[j], acc[i][j]);
        }
    }

#pragma unroll
    for (int i = 0; i < 4; ++i) {
        int row = m0 + (is << 2) + i;
        float4 o = {acc[i][0], acc[i][1], acc[i][2], acc[i][3]};
        *(float4*)(ctx + ((size_t)b * kS + row) * kH + n0 + (js << 2)) = o;
    }
}

extern "C" void kernel_launch(void* const* d_in, const int* in_sizes, int n_in,
                              void* d_out, int out_size, void* d_ws, size_t ws_size,
                              hipStream_t stream)
{
    const float* outputs = (const float*)d_in[0];
    const int*   mask    = (const int*)d_in[1];
    const float* Wa_w    = (const float*)d_in[2];
    const float* Wa_b    = (const float*)d_in[3];
    const float* Ua_w    = (const float*)d_in[4];
    const float* Ua_b    = (const float*)d_in[5];
    const float* Va_w    = (const float*)d_in[6];
    // Va_b and sum(va) cancel in softmax.

    float* attn = (float*)d_out;                          // (B,S,S)
    float* ctx  = attn + (size_t)kB * kS * kS;            // (B,S,H)
    float* EkT  = ctx;                                    // [b][h][s] — ctx region free until K4

    constexpr size_t kWlBytes = 64 * 1024;
    int* wl = (int*)d_ws;
    float* Eq = (float*)((char*)d_ws + kWlBytes);         // [4096][768] f32

    // K1 (MFMA): Eq and EkT (exp already applied)
    k1_mfma<<<dim3(kH / 96, (kB * kS) / 128, 2), 256, 0, stream>>>(
        outputs, Wa_w, Wa_b, Ua_w, Ua_b, Eq, EkT);

    // K2a + K2: scores into attn region
    k2a_worklist<<<dim3(1), 256, 0, stream>>>(mask, wl);
    k2_scores<<<dim3(1024), 256, 0, stream>>>(Eq, EkT, Va_w, mask, wl, attn);

    // K3: softmax + exact-zero masking (writes every element of attn)
    k3_softmax<<<dim3(kB * kS), 256, 0, stream>>>(attn, mask);

    // K4: contexts (writes every element of ctx, overwriting EkT scratch)
    k4_context<<<dim3(kH / 64, kS / 64, kB), 256, 0, stream>>>(attn, outputs, mask, ctx);
}

// Round 7
// 151.954 us; speedup vs baseline: 2.2389x; 1.0593x over previous
//
#include <hip/hip_runtime.h>

typedef float  f32x4   __attribute__((ext_vector_type(4)));
typedef short  short8  __attribute__((ext_vector_type(8)));
typedef unsigned short ushort8 __attribute__((ext_vector_type(8)));

constexpr int kB = 8;
constexpr int kS = 512;
constexpr int kH = 768;
constexpr int kJM = 384;   // max rows of Eqc / cols of EkTc per batch (start in [128,384))

// Values scaled by 2*log2(e) so exp2 gives e^{2x}; tanh(x) = 1 - 2/(e^{2x}+1).
// Additive constants (vb, sum(va)) cancel in softmax.
constexpr float kTanhScale = 2.8853900817779268f;

__device__ __forceinline__ float native_exp2(float x) {
    float r; asm("v_exp_f32 %0, %1" : "=v"(r) : "v"(x)); return r;
}

__device__ __forceinline__ float waveMax(float v) {
#pragma unroll
    for (int off = 32; off > 0; off >>= 1) v = fmaxf(v, __shfl_xor(v, off, 64));
    return v;
}
__device__ __forceinline__ float waveSum(float v) {
#pragma unroll
    for (int off = 32; off > 0; off >>= 1) v += __shfl_xor(v, off, 64);
    return v;
}

// ---------------- K0: flat f32 -> bf16 hi/lo split for X, Wa, Ua.
// X: 786432 float4s, Wa/Ua: 147456 each. Total 1081344 = 4224 blocks * 256.
__global__ __launch_bounds__(256) void k0_convert(
    const float* __restrict__ X, const float* __restrict__ Wa, const float* __restrict__ Ua,
    unsigned short* __restrict__ Xhi, unsigned short* __restrict__ Xlo,
    unsigned short* __restrict__ Wahi, unsigned short* __restrict__ Walo,
    unsigned short* __restrict__ Uahi, unsigned short* __restrict__ Ualo)
{
    const int i4 = blockIdx.x * 256 + threadIdx.x;
    const float* src; unsigned short *hi, *lo; int off;
    if (i4 < 786432)      { src = X;  hi = Xhi;  lo = Xlo;  off = i4; }
    else if (i4 < 933888) { src = Wa; hi = Wahi; lo = Walo; off = i4 - 786432; }
    else                  { src = Ua; hi = Uahi; lo = Ualo; off = i4 - 933888; }

    float4 v = *(const float4*)(src + (size_t)off * 4);
    unsigned short h[4], l[4];
#pragma unroll
    for (int c = 0; c < 4; ++c) {
        float x = (&v.x)[c];
        unsigned u = __float_as_uint(x);
        h[c] = (unsigned short)(u >> 16);
        float hf = __uint_as_float(u & 0xFFFF0000u);
        l[c] = (unsigned short)(__float_as_uint(x - hf) >> 16);
    }
    *(ushort4*)(hi + (size_t)off * 4) = make_ushort4(h[0], h[1], h[2], h[3]);
    *(ushort4*)(lo + (size_t)off * 4) = make_ushort4(l[0], l[1], l[2], l[3]);
}

// ---------------- K1 (MFMA): z=0: Eqc[b][jj][n] = exp2((X·Wa^T+b)*s), jj = t-start (rows t>=start)
//                             z=1: EkTc[b][n][s] = exp2((X·Ua^T+b)*s), cols s < start
// BM=128, BN=96, BK=32; 4 waves each a 64x48 quadrant; bf16 3-product (hi*hi+lo*hi+hi*lo).
__global__ __launch_bounds__(256) void k1_mfma(
    const unsigned short* __restrict__ Xhi, const unsigned short* __restrict__ Xlo,
    const unsigned short* __restrict__ W0hi, const unsigned short* __restrict__ W0lo,
    const unsigned short* __restrict__ W1hi, const unsigned short* __restrict__ W1lo,
    const float* __restrict__ b0, const float* __restrict__ b1,
    const int* __restrict__ mask,
    float* __restrict__ Eqc, float* __restrict__ EkTc)
{
    // LDS: Ahi [128][40]us @0 | Alo @10240 | Bhi [96][40]us @20480 | Blo @28160
    // z=1 epilogue aliases as float stage[128][97] (49664 B)
    __shared__ char smem[49664];
    unsigned short* Ahi = (unsigned short*)smem;
    unsigned short* Alo = (unsigned short*)(smem + 10240);
    unsigned short* Bhi = (unsigned short*)(smem + 20480);
    unsigned short* Blo = (unsigned short*)(smem + 28160);

    const int z = blockIdx.z;
    const unsigned short* Whi = z ? W1hi : W0hi;
    const unsigned short* Wlo = z ? W1lo : W0lo;
    const float* bias = z ? b1 : b0;

    const int m0 = blockIdx.y * 128;
    const int n0 = blockIdx.x * 96;
    const int t  = threadIdx.x;
    const int bI = m0 >> 9;            // batch (128 | 512: never straddles)
    const int lb = m0 & (kS - 1);      // local row base within batch
    const int start = mask[2 * bI];

    // dead-block early exit (block-uniform, before any barrier)
    if (z == 0) { if (lb + 128 <= start) return; }
    else        { if (lb >= start) return; }

    // staging roles: 2 threads per row, 16 bf16 each
    const int ar = t >> 1, ko = (t & 1) << 4;
    const bool doB = (ar < 96);
    const size_t aoff = (size_t)(m0 + ar) * kH + ko;
    const size_t woff = (size_t)(n0 + ar) * kH + ko;

    // mfma roles
    const int wid = t >> 6, lane = t & 63;
    const int wr = wid >> 1, wc = wid & 1;
    const int lr = lane & 15, lk = (lane >> 4) << 3;

    f32x4 acc[4][3];
#pragma unroll
    for (int mi = 0; mi < 4; ++mi)
#pragma unroll
        for (int ni = 0; ni < 3; ++ni)
#pragma unroll
            for (int r = 0; r < 4; ++r) acc[mi][ni][r] = 0.0f;

    for (int h0 = 0; h0 < kH; h0 += 32) {
        ushort8 ah0 = *(const ushort8*)(Xhi + aoff + h0);
        ushort8 ah1 = *(const ushort8*)(Xhi + aoff + h0 + 8);
        ushort8 al0 = *(const ushort8*)(Xlo + aoff + h0);
        ushort8 al1 = *(const ushort8*)(Xlo + aoff + h0 + 8);
        ushort8 bh0, bh1, bl0, bl1;
        if (doB) {
            bh0 = *(const ushort8*)(Whi + woff + h0);
            bh1 = *(const ushort8*)(Whi + woff + h0 + 8);
            bl0 = *(const ushort8*)(Wlo + woff + h0);
            bl1 = *(const ushort8*)(Wlo + woff + h0 + 8);
        }
        __syncthreads();
        *(ushort8*)(Ahi + ar * 40 + ko)     = ah0;
        *(ushort8*)(Ahi + ar * 40 + ko + 8) = ah1;
        *(ushort8*)(Alo + ar * 40 + ko)     = al0;
        *(ushort8*)(Alo + ar * 40 + ko + 8) = al1;
        if (doB) {
            *(ushort8*)(Bhi + ar * 40 + ko)     = bh0;
            *(ushort8*)(Bhi + ar * 40 + ko + 8) = bh1;
            *(ushort8*)(Blo + ar * 40 + ko)     = bl0;
            *(ushort8*)(Blo + ar * 40 + ko + 8) = bl1;
        }
        __syncthreads();

        short8 ah[4], al_[4], bh[3], bl[3];
#pragma unroll
        for (int mi = 0; mi < 4; ++mi) {
            const int row = wr * 64 + mi * 16 + lr;
            ah[mi]  = *(const short8*)(Ahi + row * 40 + lk);
            al_[mi] = *(const short8*)(Alo + row * 40 + lk);
        }
#pragma unroll
        for (int ni = 0; ni < 3; ++ni) {
            const int row = wc * 48 + ni * 16 + lr;
            bh[ni] = *(const short8*)(Bhi + row * 40 + lk);
            bl[ni] = *(const short8*)(Blo + row * 40 + lk);
        }
#pragma unroll
        for (int mi = 0; mi < 4; ++mi)
#pragma unroll
            for (int ni = 0; ni < 3; ++ni)
                acc[mi][ni] = __builtin_amdgcn_mfma_f32_16x16x32_bf16(ah[mi], bh[ni], acc[mi][ni], 0, 0, 0);
#pragma unroll
        for (int mi = 0; mi < 4; ++mi)
#pragma unroll
            for (int ni = 0; ni < 3; ++ni)
                acc[mi][ni] = __builtin_amdgcn_mfma_f32_16x16x32_bf16(al_[mi], bh[ni], acc[mi][ni], 0, 0, 0);
#pragma unroll
        for (int mi = 0; mi < 4; ++mi)
#pragma unroll
            for (int ni = 0; ni < 3; ++ni)
                acc[mi][ni] = __builtin_amdgcn_mfma_f32_16x16x32_bf16(ah[mi], bl[ni], acc[mi][ni], 0, 0, 0);
    }

    // C/D frag: col = lane&15, row = (lane>>4)*4 + reg
    if (z == 0) {
        // compacted row store: jj = (global row & 511) - start, keep jj >= 0
#pragma unroll
        for (int mi = 0; mi < 4; ++mi)
#pragma unroll
            for (int ni = 0; ni < 3; ++ni) {
                const int ml = lb + wr * 64 + mi * 16 + ((lane >> 4) << 2);
                const int ng = n0 + wc * 48 + ni * 16 + lr;
                const float bn = bias[ng];
#pragma unroll
                for (int r = 0; r < 4; ++r) {
                    const int jj = ml + r - start;
                    if (jj >= 0)
                        Eqc[((size_t)bI * kJM + jj) * kH + ng] =
                            native_exp2((acc[mi][ni][r] + bn) * kTanhScale);
                }
            }
    } else {
        __syncthreads();                       // tile reads done before aliasing LDS
        float* stg = (float*)smem;             // [128][97]
#pragma unroll
        for (int mi = 0; mi < 4; ++mi)
#pragma unroll
            for (int ni = 0; ni < 3; ++ni) {
                const int ml = wr * 64 + mi * 16 + ((lane >> 4) << 2);
                const int nl = wc * 48 + ni * 16 + lr;
                const float bn = bias[n0 + nl];
#pragma unroll
                for (int r = 0; r < 4; ++r)
                    stg[(ml + r) * 97 + nl] = native_exp2((acc[mi][ni][r] + bn) * kTanhScale);
            }
        __syncthreads();
        const int s4 = (t & 31) << 2, hb_ = t >> 5;
        const int sg = lb + s4;
#pragma unroll
        for (int u = 0; u < 12; ++u) {
            const int h = (u << 3) + hb_;
            float o[4] = { stg[(s4 + 0) * 97 + h], stg[(s4 + 1) * 97 + h],
                           stg[(s4 + 2) * 97 + h], stg[(s4 + 3) * 97 + h] };
            float* dst = EkTc + ((size_t)bI * kH + n0 + h) * kJM + sg;
            if (sg + 3 < start) {
                *(float4*)dst = make_float4(o[0], o[1], o[2], o[3]);
            } else {
#pragma unroll
                for (int e2 = 0; e2 < 4; ++e2)
                    if (sg + e2 < start) dst[e2] = o[e2];
            }
        }
    }
}

// ---------------- K2a: work list of (b, j-pair, k-wave, h-chunk) items.
__global__ void k2a_worklist(const int* __restrict__ mask, int* __restrict__ wl)
{
    __shared__ int ne[kB], off[kB];
    const int tid = threadIdx.x;
    if (tid < kB) {
        int start = mask[2 * tid];
        ne[tid] = ((kS - start + 1) >> 1) * ((start + 63) >> 6) * 2;
    }
    __syncthreads();
    if (tid == 0) {
        int s = 0;
        for (int b = 0; b < kB; ++b) { off[b] = s; s += ne[b]; }
        wl[0] = s;
    }
    __syncthreads();
    for (int b = 0; b < kB; ++b) {
        int start = mask[2 * b];
        int nkw = (start + 63) >> 6;
        int n = ne[b], base = off[b];
        for (int t = tid; t < n; t += blockDim.x) {
            int c = t & 1, p = t >> 1;
            int jt = p / nkw, kt = p - jt * nkw;
            wl[1 + base + t] = (b << 16) | (jt << 8) | (kt << 1) | c;
        }
    }
}

// ---------------- K2: one wave per item; lane = k; 2 j-rows; 384-wide h-chunk.
// score~ = -2 * sum_h va[h] * rcp(Eq[b,j,h]*Ek[b,h,k] + 1)
__global__ __launch_bounds__(256) void k2_scores(
    const float* __restrict__ Eqc, const float* __restrict__ EkTc,
    const float* __restrict__ va, const int* __restrict__ mask,
    const int* __restrict__ wl, float* __restrict__ part0, float* __restrict__ part1)
{
    const int ntiles = wl[0];
    const int lane = threadIdx.x & 63;
    const int wslot = (blockIdx.x << 2) | (threadIdx.x >> 6);
    const int nslots = gridDim.x << 2;

    for (int w = wslot; w < ntiles; w += nslots) {
        const int e = __builtin_amdgcn_readfirstlane(wl[1 + w]);
        const int b = e >> 16, jt = (e >> 8) & 255, ktc = e & 255;
        const int kt = ktc >> 1, c = ktc & 1;
        const int start = __builtin_amdgcn_readfirstlane(mask[2 * b]);
        const int jmax = kS - start;
        const int j0 = jt << 1, k0 = kt << 6;
        const int hbase = c * 384;

        const float* eq0 = Eqc + ((size_t)b * kJM + j0) * kH + hbase;
        const float* eq1 = eq0 + kH;
        const float* ekp = EkTc + ((size_t)b * kH + hbase) * kJM + k0 + lane;
        const float* vap = va + hbase;

        float a0 = 0.0f, a1 = 0.0f;
        float eA[8], eB[8];
#pragma unroll
        for (int c2 = 0; c2 < 8; ++c2) eA[c2] = ekp[(size_t)c2 * kJM];
#pragma unroll
        for (int c2 = 0; c2 < 8; ++c2) eB[c2] = ekp[(size_t)(8 + c2) * kJM];

        for (int h0 = 0; h0 < 384; h0 += 16) {
            const bool more = (h0 + 16) < 384;
            float nA[8], nB[8];
            if (more) {
#pragma unroll
                for (int c2 = 0; c2 < 8; ++c2) nA[c2] = ekp[(size_t)(h0 + 16 + c2) * kJM];
            }
#pragma unroll
            for (int c2 = 0; c2 < 8; ++c2) {
                const float vc = vap[h0 + c2];
                float r0 = __builtin_amdgcn_rcpf(fmaf(eq0[h0 + c2], eA[c2], 1.0f));
                float r1 = __builtin_amdgcn_rcpf(fmaf(eq1[h0 + c2], eA[c2], 1.0f));
                a0 = fmaf(vc, r0, a0);
                a1 = fmaf(vc, r1, a1);
            }
            if (more) {
#pragma unroll
                for (int c2 = 0; c2 < 8; ++c2) nB[c2] = ekp[(size_t)(h0 + 24 + c2) * kJM];
#pragma unroll
                for (int c2 = 0; c2 < 8; ++c2) {
                    const float vc = vap[h0 + 8 + c2];
                    float r0 = __builtin_amdgcn_rcpf(fmaf(eq0[h0 + 8 + c2], eB[c2], 1.0f));
                    float r1 = __builtin_amdgcn_rcpf(fmaf(eq1[h0 + 8 + c2], eB[c2], 1.0f));
                    a0 = fmaf(vc, r0, a0);
                    a1 = fmaf(vc, r1, a1);
                }
#pragma unroll
                for (int c2 = 0; c2 < 8; ++c2) { eA[c2] = nA[c2]; eB[c2] = nB[c2]; }
            } else {
#pragma unroll
                for (int c2 = 0; c2 < 8; ++c2) {
                    const float vc = vap[h0 + 8 + c2];
                    float r0 = __builtin_amdgcn_rcpf(fmaf(eq0[h0 + 8 + c2], eB[c2], 1.0f));
                    float r1 = __builtin_amdgcn_rcpf(fmaf(eq1[h0 + 8 + c2], eB[c2], 1.0f));
                    a0 = fmaf(vc, r0, a0);
                    a1 = fmaf(vc, r1, a1);
                }
            }
        }

        float* srow = (c ? part1 : part0) + ((size_t)b * kS + j0) * kS + k0 + lane;
        if (j0 < jmax)     srow[0]  = -2.0f * a0;
        if (j0 + 1 < jmax) srow[kS] = -2.0f * a1;
    }
}

// ---------------- K3: sum partials + row softmax over k < start; exact zeros elsewhere.
__global__ __launch_bounds__(256) void k3_softmax(
    float* __restrict__ attn, const float* __restrict__ part1,
    const int* __restrict__ mask)
{
    const int bx = blockIdx.x;
    const int b = bx >> 9;
    const int j = bx & (kS - 1);
    const int start = mask[2 * b];
    float* row = attn + ((size_t)b * kS + j) * kS;
    const int tid = threadIdx.x;

    if (j >= kS - start) {
        row[tid] = 0.0f;
        row[tid + 256] = 0.0f;
        return;
    }

    const float* p1row = part1 + ((size_t)b * kS + j) * kS;
    float v0 = (tid < start) ? row[tid] + p1row[tid] : -1e30f;
    float v1 = (tid + 256 < start) ? row[tid + 256] + p1row[tid + 256] : -1e30f;

    __shared__ float red[4];
    const int wid = tid >> 6;

    float m = waveMax(fmaxf(v0, v1));
    if ((tid & 63) == 0) red[wid] = m;
    __syncthreads();
    m = fmaxf(fmaxf(red[0], red[1]), fmaxf(red[2], red[3]));
    __syncthreads();

    float e0 = (tid < start) ? __expf(v0 - m) : 0.0f;
    float e1 = (tid + 256 < start) ? __expf(v1 - m) : 0.0f;
    float s = waveSum(e0 + e1);
    if ((tid & 63) == 0) red[wid] = s;
    __syncthreads();
    s = red[0] + red[1] + red[2] + red[3];

    float inv = __builtin_amdgcn_rcpf(s);
    row[tid] = e0 * inv;
    row[tid + 256] = e1 * inv;
}

// ---------------- K4: ctx[b,j,h] = sum_k attn[b,j,k] * outputs[b,k,h], K bounded by start.
__global__ __launch_bounds__(256) void k4_context(
    const float* __restrict__ attn, const float* __restrict__ outs,
    const int* __restrict__ mask, float* __restrict__ ctx)
{
    const int b = blockIdx.z;
    const int start = mask[2 * b];
    const int kmax = (start + 15) & ~15;
    const int m0 = blockIdx.y * 64;
    const int n0 = blockIdx.x * 64;

    __shared__ float As[16][68];
    __shared__ float Bs[16][68];

    const int tid = threadIdx.x;
    const int lrow = tid >> 2;
    const int lk4  = (tid & 3) << 2;
    const int brow = tid >> 4;
    const int bh4  = (tid & 15) << 2;
    const int is = tid >> 4;
    const int js = tid & 15;

    const float* arow = attn + ((size_t)b * kS + m0 + lrow) * kS + lk4;
    const float* bbase = outs + (size_t)b * kS * kH + n0 + bh4;

    float acc[4][4] = {};

    for (int k0 = 0; k0 < kmax; k0 += 16) {
        float4 av = *(const float4*)(arow + k0);
        float4 bv = *(const float4*)(bbase + (size_t)(k0 + brow) * kH);
        __syncthreads();
        As[lk4 + 0][lrow] = av.x;
        As[lk4 + 1][lrow] = av.y;
        As[lk4 + 2][lrow] = av.z;
        As[lk4 + 3][lrow] = av.w;
        *(float4*)&Bs[brow][bh4] = bv;
        __syncthreads();
#pragma unroll
        for (int kk = 0; kk < 16; ++kk) {
            const float* ap = &As[kk][is << 2];
            const float* bp = &Bs[kk][js << 2];
            float aa[4], bb[4];
#pragma unroll
            for (int c = 0; c < 4; ++c) { aa[c] = ap[c]; bb[c] = bp[c]; }
#pragma unroll
            for (int i = 0; i < 4; ++i)
#pragma unroll
                for (int j = 0; j < 4; ++j)
                    acc[i][j] = fmaf(aa[i], bb[j], acc[i][j]);
        }
    }

#pragma unroll
    for (int i = 0; i < 4; ++i) {
        int row = m0 + (is << 2) + i;
        float4 o = {acc[i][0], acc[i][1], acc[i][2], acc[i][3]};
        *(float4*)(ctx + ((size_t)b * kS + row) * kH + n0 + (js << 2)) = o;
    }
}

extern "C" void kernel_launch(void* const* d_in, const int* in_sizes, int n_in,
                              void* d_out, int out_size, void* d_ws, size_t ws_size,
                              hipStream_t stream)
{
    const float* outputs = (const float*)d_in[0];
    const int*   mask    = (const int*)d_in[1];
    const float* Wa_w    = (const float*)d_in[2];
    const float* Wa_b    = (const float*)d_in[3];
    const float* Ua_w    = (const float*)d_in[4];
    const float* Ua_b    = (const float*)d_in[5];
    const float* Va_w    = (const float*)d_in[6];
    // Va_b and sum(va) cancel in softmax.

    float* attn = (float*)d_out;                          // (B,S,S) 8.39 MB
    float* ctx  = attn + (size_t)kB * kS * kS;            // (B,S,H) 12.58 MB

    // Regions reused over the launch timeline (stream-ordered):
    //   ctx:  [K0..K1] Xhi/Xlo bf16 pair  -> [K2..K3] part1 scores -> [K4] contexts
    //   attn: [K0..K1] W hi/lo pairs      -> [K2..]   part0 scores / attentions
    unsigned short* Xhi  = (unsigned short*)ctx;                    // 6.29 MB
    unsigned short* Xlo  = Xhi + (size_t)kB * kS * kH;              // 6.29 MB
    unsigned short* Wahi = (unsigned short*)attn;                   // 1.18 MB each
    unsigned short* Walo = Wahi + (size_t)kH * kH;
    unsigned short* Uahi = Walo + (size_t)kH * kH;
    unsigned short* Ualo = Uahi + (size_t)kH * kH;
    float* part1 = ctx;

    // ws: [wl 128KB][Eqc 9.44MB][EkTc 9.44MB] = 19.0 MB
    int* wl = (int*)d_ws;
    float* Eqc  = (float*)((char*)d_ws + 131072);
    float* EkTc = Eqc + (size_t)kB * kJM * kH;

    // K0: bf16 hi/lo pre-split of X, Wa, Ua
    k0_convert<<<dim3(4224), 256, 0, stream>>>(
        outputs, Wa_w, Ua_w, Xhi, Xlo, Wahi, Walo, Uahi, Ualo);

    // K1 (MFMA): Eqc (compacted rows) and EkTc (compacted cols), exp applied
    k1_mfma<<<dim3(kH / 96, (kB * kS) / 128, 2), 256, 0, stream>>>(
        Xhi, Xlo, Wahi, Walo, Uahi, Ualo, Wa_b, Ua_b, mask, Eqc, EkTc);

    // K2a + K2: score partials (h-chunks) into attn (c=0) and part1 (c=1)
    k2a_worklist<<<dim3(1), 256, 0, stream>>>(mask, wl);
    k2_scores<<<dim3(2048), 256, 0, stream>>>(Eqc, EkTc, Va_w, mask, wl, attn, part1);

    // K3: sum partials + softmax + exact-zero masking (writes every element of attn)
    k3_softmax<<<dim3(kB * kS), 256, 0, stream>>>(attn, part1, mask);

    // K4: contexts (writes every element of ctx, overwriting part1 scratch)
    k4_context<<<dim3(kH / 64, kS / 64, kB), 256, 0, stream>>>(attn, outputs, mask, ctx);
}